// Round 9
// baseline (276.058 us; speedup 1.0000x reference)
//
#include <hip/hip_runtime.h>
#include <hip/hip_bf16.h>

#define S_LEN 2048
#define D_DIM 1024
#define NH    16
#define NEG_BIG (-1.0e30f)

// epilogue modes for gemm_bt
#define EPI_NORMROPE 1   // RMSNorm + RoPE, store bf16 row-major (Q,K)
#define EPI_VMIX_T   2   // v-mix with v1, store bf16 TRANSPOSED (V -> Vt_g[d][s])
#define EPI_F32      3   // plain f32 row-major store (out-proj)

typedef __attribute__((ext_vector_type(8))) short bf16x8;
typedef __attribute__((ext_vector_type(4))) float f32x4;
typedef const __attribute__((address_space(1))) unsigned char gu8_t;
typedef __attribute__((address_space(3))) unsigned char lu8_t;

__device__ __forceinline__ float bf2f(unsigned short h) {
    union { unsigned int u; float f; } v; v.u = ((unsigned int)h) << 16; return v.f;
}
__device__ __forceinline__ unsigned short f2b(float f) {   // RNE f32->bf16 raw bits
    union { float f; unsigned int u; } v; v.f = f;
    unsigned int u = v.u;
    return (unsigned short)((u + 0x7FFFu + ((u >> 16) & 1u)) >> 16);
}

// one-shot f32 -> bf16 conversion of x + 4 weights (externals measured f32, r4-r8).
__global__ __launch_bounds__(256)
void to_bf16(const float* __restrict__ x,  const float* __restrict__ wq,
             const float* __restrict__ wk, const float* __restrict__ wv,
             const float* __restrict__ wo,
             unsigned short* __restrict__ xb,  unsigned short* __restrict__ wqb,
             unsigned short* __restrict__ wkb, unsigned short* __restrict__ wvb,
             unsigned short* __restrict__ wob)
{
    const int z = blockIdx.y;
    const float* s; unsigned short* d; int n;
    switch (z) {
        case 0: s = x;  d = xb;  n = S_LEN * D_DIM; break;
        case 1: s = wq; d = wqb; n = D_DIM * D_DIM; break;
        case 2: s = wk; d = wkb; n = D_DIM * D_DIM; break;
        case 3: s = wv; d = wvb; n = D_DIM * D_DIM; break;
        default: s = wo; d = wob; n = D_DIM * D_DIM; break;
    }
    int i8 = blockIdx.x * 256 + threadIdx.x;
    if (i8 * 8 >= n) return;
    const float* sp = s + (size_t)i8 * 8;
    float4 lo = *(const float4*)sp, hi = *(const float4*)(sp + 4);
    uint4 p;
    p.x = f2b(lo.x) | ((unsigned)f2b(lo.y) << 16);
    p.y = f2b(lo.z) | ((unsigned)f2b(lo.w) << 16);
    p.z = f2b(hi.x) | ((unsigned)f2b(hi.y) << 16);
    p.w = f2b(hi.z) | ((unsigned)f2b(hi.w) << 16);
    *(uint4*)(d + (size_t)i8 * 8) = p;
}

// C = A[M,K] * B[N,K]^T, bf16 inputs, global_load_lds(16B) staging into
// unpadded [128][32] LDS (m97 contract). Epilogue per 'epi' (wave-uniform).
__global__ __launch_bounds__(256, 2)
void gemm_bt(const unsigned short* __restrict__ A,
             const unsigned short* __restrict__ B0, const unsigned short* __restrict__ B1,
             const unsigned short* __restrict__ B2,
             void* __restrict__ C0, void* __restrict__ C1, void* __restrict__ C2,
             const float* __restrict__ vmix, const float* __restrict__ lam,
             int epiPack)
{
    const int which = blockIdx.z;
    const unsigned short* Bp = (which == 0) ? B0 : ((which == 1) ? B1 : B2);
    void* C = (which == 0) ? C0 : ((which == 1) ? C1 : C2);
    const int epi = (epiPack >> (8 * which)) & 0xff;
    const int tn = blockIdx.x * 128;
    const int tm = blockIdx.y * 128;

    __shared__ unsigned short Asl[128 * 32];   // unpadded: global_load_lds contract
    __shared__ unsigned short Bsl[128 * 32];

    const int t    = threadIdx.x;
    const int lane = t & 63;
    const int wave = t >> 6;
    const int wm   = (wave >> 1) * 64;
    const int wn   = (wave & 1) * 64;
    const int lrow = lane & 15;
    const int quad = lane >> 4;
    const int srow = lane >> 2;
    const int scol = (lane & 3) * 8;

    f32x4 acc[4][4];
    #pragma unroll
    for (int i = 0; i < 4; ++i)
        #pragma unroll
        for (int j = 0; j < 4; ++j) {
            f32x4 z = {0.f, 0.f, 0.f, 0.f};
            acc[i][j] = z;
        }

    for (int k0 = 0; k0 < D_DIM; k0 += 32) {
        #pragma unroll
        for (int rep = 0; rep < 2; ++rep) {
            int grp = wave * 2 + rep;               // 0..7 (16 rows each)
            int row = grp * 16 + srow;
            __builtin_amdgcn_global_load_lds(
                (gu8_t*)(A + (size_t)(tm + row) * D_DIM + k0 + scol),
                (lu8_t*)&Asl[grp * 512], 16, 0, 0);
            __builtin_amdgcn_global_load_lds(
                (gu8_t*)(Bp + (size_t)(tn + row) * D_DIM + k0 + scol),
                (lu8_t*)&Bsl[grp * 512], 16, 0, 0);
        }
        __syncthreads();
        bf16x8 af[4], bfr[4];
        #pragma unroll
        for (int i = 0; i < 4; ++i)
            af[i] = *(const bf16x8*)(&Asl[(wm + i * 16 + lrow) * 32 + quad * 8]);
        #pragma unroll
        for (int j = 0; j < 4; ++j)
            bfr[j] = *(const bf16x8*)(&Bsl[(wn + j * 16 + lrow) * 32 + quad * 8]);
        #pragma unroll
        for (int i = 0; i < 4; ++i)
            #pragma unroll
            for (int j = 0; j < 4; ++j)
                acc[i][j] = __builtin_amdgcn_mfma_f32_16x16x32_bf16(af[i], bfr[j], acc[i][j], 0, 0, 0);
        __syncthreads();
    }

    if (epi == EPI_NORMROPE) {
        // wave covers cols [tn+wn, tn+wn+64) = one head. RoPE pair (i, i+32) = (j, j+2).
        #pragma unroll
        for (int i = 0; i < 4; ++i) {
            #pragma unroll
            for (int r = 0; r < 4; ++r) {
                int row = tm + wm + i * 16 + quad * 4 + r;   // seq position (m89/m91 C-map)
                float v0 = acc[i][0][r], v1 = acc[i][1][r];
                float v2 = acc[i][2][r], v3 = acc[i][3][r];
                float ss = v0 * v0 + v1 * v1 + v2 * v2 + v3 * v3;
                ss += __shfl_xor(ss, 1); ss += __shfl_xor(ss, 2);
                ss += __shfl_xor(ss, 4); ss += __shfl_xor(ss, 8);   // 16-lane group = full head
                float rms = rsqrtf(ss * (1.f / 64.f) + 1.1920929e-7f);
                v0 *= rms; v1 *= rms; v2 *= rms; v3 *= rms;
                float fs = (float)row;
                float a0 = fs * exp2f(-0.41524101186092030f * (float)lrow);        // 10000^(-2i/64)
                float a1 = fs * exp2f(-0.41524101186092030f * (float)(16 + lrow));
                float s0, c0, s1, c1;
                __sincosf(a0, &s0, &c0);
                __sincosf(a1, &s1, &c1);
                unsigned short* Cb = (unsigned short*)C;
                size_t base = (size_t)row * D_DIM + tn + wn + lrow;
                Cb[base]      = f2b(v0 * c0 + v2 * s0);
                Cb[base + 16] = f2b(v1 * c1 + v3 * s1);
                Cb[base + 32] = f2b(-v0 * s0 + v2 * c0);
                Cb[base + 48] = f2b(-v1 * s1 + v3 * c1);
            }
        }
    } else if (epi == EPI_VMIX_T) {
        float lamf = *lam;
        #pragma unroll
        for (int i = 0; i < 4; ++i) {
            int cm0 = tm + wm + i * 16 + quad * 4;
            #pragma unroll
            for (int j = 0; j < 4; ++j) {
                int cn = tn + wn + j * 16 + lrow;
                ushort4 pk;
                float vals[4];
                #pragma unroll
                for (int r = 0; r < 4; ++r) {
                    size_t idx = (size_t)(cm0 + r) * D_DIM + cn;
                    vals[r] = (1.f - lamf) * acc[i][j][r] + lamf * vmix[idx];
                }
                pk.x = f2b(vals[0]); pk.y = f2b(vals[1]);
                pk.z = f2b(vals[2]); pk.w = f2b(vals[3]);
                *(ushort4*)((unsigned short*)C + (size_t)cn * S_LEN + cm0) = pk;
            }
        }
    } else {   // EPI_F32
        #pragma unroll
        for (int i = 0; i < 4; ++i) {
            int cm0 = tm + wm + i * 16 + quad * 4;
            #pragma unroll
            for (int j = 0; j < 4; ++j) {
                int cn = tn + wn + j * 16 + lrow;
                #pragma unroll
                for (int r = 0; r < 4; ++r)
                    ((float*)C)[(size_t)(cm0 + r) * D_DIM + cn] = acc[i][j][r];
            }
        }
    }
}

// Barrier-free MFMA flash attention: ONE WAVE per 16-row Q-tile per head.
// K and Vt B-fragments load DIRECTLY from global (L2-served, 16 rows x 64B per
// instruction) — no K/V LDS, no __syncthreads, waves fully decoupled. Only the
// P C-layout -> A-layout round-trip uses (per-wave-private) LDS; same-wave DS
// ordering via lgkmcnt, no barrier. grid 2048 = 128 q-tiles x 16 heads,
// long/short interleaved for load balance. block = 64 (one wave).
__global__ __launch_bounds__(64)
void attn_mfma(const unsigned short* Qb,
               const unsigned short* __restrict__ Kb,
               const unsigned short* __restrict__ Vtg,
               unsigned short* Ob)
{
    const int b = blockIdx.x;
    const int i = b & 127;
    const int h = b >> 7;
    const int qt16 = (i & 1) ? (127 - (i >> 1)) : (i >> 1);  // interleave long/short
    const int l    = threadIdx.x & 63;
    const int l15  = l & 15;
    const int quad = l >> 4;
    const int hco  = h * 64;

    __shared__ unsigned short Ps[16][72];    // per-wave P tile (block = 1 wave)

    // Q A-frags: A[m=l15][k=quad*8+j], k-chunks 0 and 32
    const unsigned short* qrow = Qb + (size_t)(qt16 * 16 + l15) * D_DIM + hco;
    bf16x8 qf0 = *(const bf16x8*)(qrow + quad * 8);
    bf16x8 qf1 = *(const bf16x8*)(qrow + 32 + quad * 8);

    f32x4 oac[4];
    #pragma unroll
    for (int nt = 0; nt < 4; ++nt) { f32x4 z = {0.f,0.f,0.f,0.f}; oac[nt] = z; }
    float m_run[4], l_run[4];
    #pragma unroll
    for (int r = 0; r < 4; ++r) { m_run[r] = NEG_BIG; l_run[r] = 0.f; }

    const int jend = (qt16 >> 2) + 1;
    const int row_base = qt16 * 16 + quad * 4;   // C-layout row = quad*4 + reg

    for (int j = 0; j < jend; ++j) {
        // K B-frags direct from global: B[n=l15][k] at key row j*64 + nt*16 + l15
        bf16x8 kf[4][2];
        #pragma unroll
        for (int nt = 0; nt < 4; ++nt) {
            const unsigned short* kp = Kb + (size_t)(j * 64 + nt * 16 + l15) * D_DIM + hco;
            kf[nt][0] = *(const bf16x8*)(kp + quad * 8);
            kf[nt][1] = *(const bf16x8*)(kp + 32 + quad * 8);
        }
        // V B-frags direct from global (pre-transposed): row = dim hco+nt*16+l15, cols = keys
        bf16x8 vf[4][2];
        #pragma unroll
        for (int nt = 0; nt < 4; ++nt) {
            const unsigned short* vp = Vtg + (size_t)(hco + nt * 16 + l15) * S_LEN + j * 64;
            vf[nt][0] = *(const bf16x8*)(vp + quad * 8);
            vf[nt][1] = *(const bf16x8*)(vp + 32 + quad * 8);
        }

        // S = Q K^T (16 rows x 64 keys)
        f32x4 sac[4];
        #pragma unroll
        for (int nt = 0; nt < 4; ++nt) {
            f32x4 z = {0.f,0.f,0.f,0.f};
            z = __builtin_amdgcn_mfma_f32_16x16x32_bf16(qf0, kf[nt][0], z, 0, 0, 0);
            z = __builtin_amdgcn_mfma_f32_16x16x32_bf16(qf1, kf[nt][1], z, 0, 0, 0);
            sac[nt] = z;
        }

        // scale + causal mask + row max
        float sv[4][4];
        float mx[4] = {NEG_BIG, NEG_BIG, NEG_BIG, NEG_BIG};
        #pragma unroll
        for (int nt = 0; nt < 4; ++nt) {
            int key_g = j * 64 + nt * 16 + l15;
            #pragma unroll
            for (int r = 0; r < 4; ++r) {
                float s = sac[nt][r] * 0.125f;
                if (key_g > row_base + r) s = NEG_BIG;
                sv[nt][r] = s;
                mx[r] = fmaxf(mx[r], s);
            }
        }
        #pragma unroll
        for (int r = 0; r < 4; ++r) {
            #pragma unroll
            for (int d = 1; d < 16; d <<= 1) mx[r] = fmaxf(mx[r], __shfl_xor(mx[r], d));
        }

        float alpha[4], ls[4];
        #pragma unroll
        for (int r = 0; r < 4; ++r) {
            float mn = fmaxf(m_run[r], mx[r]);
            alpha[r] = __expf(fminf(fmaxf(m_run[r] - mn, -80.f), 0.f));
            m_run[r] = mn;
            ls[r] = 0.f;
        }
        #pragma unroll
        for (int nt = 0; nt < 4; ++nt) {
            #pragma unroll
            for (int r = 0; r < 4; ++r) {
                float pe = __expf(fminf(fmaxf(sv[nt][r] - m_run[r], -80.f), 0.f));
                ls[r] += pe;
                Ps[quad * 4 + r][nt * 16 + l15] = f2b(pe);
            }
        }
        #pragma unroll
        for (int r = 0; r < 4; ++r) {
            #pragma unroll
            for (int d = 1; d < 16; d <<= 1) ls[r] += __shfl_xor(ls[r], d);
            l_run[r] = l_run[r] * alpha[r] + ls[r];
        }
        #pragma unroll
        for (int nt = 0; nt < 4; ++nt) {
            #pragma unroll
            for (int r = 0; r < 4; ++r) oac[nt][r] *= alpha[r];
        }

        // P: C-layout -> A-layout via per-wave LDS (lgkmcnt orders write->read)
        bf16x8 pf0 = *(const bf16x8*)&Ps[l15][quad * 8];
        bf16x8 pf1 = *(const bf16x8*)&Ps[l15][32 + quad * 8];
        #pragma unroll
        for (int nt = 0; nt < 4; ++nt) {
            oac[nt] = __builtin_amdgcn_mfma_f32_16x16x32_bf16(pf0, vf[nt][0], oac[nt], 0, 0, 0);
            oac[nt] = __builtin_amdgcn_mfma_f32_16x16x32_bf16(pf1, vf[nt][1], oac[nt], 0, 0, 0);
        }
    }

    float inv[4];
    #pragma unroll
    for (int r = 0; r < 4; ++r) inv[r] = 1.f / l_run[r];   // >= 1 (diagonal unmasked)
    #pragma unroll
    for (int nt = 0; nt < 4; ++nt) {
        #pragma unroll
        for (int r = 0; r < 4; ++r)
            Ob[(size_t)(row_base + r) * D_DIM + hco + nt * 16 + l15] = f2b(oac[nt][r] * inv[r]);
    }
}

// v1 passthrough (f32), 16B chunks.
__global__ __launch_bounds__(256)
void copy_v1(const uint4* __restrict__ src, uint4* __restrict__ dst) {
    int i = blockIdx.x * 256 + threadIdx.x;
    dst[i] = src[i];
}

extern "C" void kernel_launch(void* const* d_in, const int* in_sizes, int n_in,
                              void* d_out, int out_size, void* d_ws, size_t ws_size,
                              hipStream_t stream)
{
    const float* x    = (const float*)d_in[0];
    const float* v1   = (const float*)d_in[1];
    const float* Wq   = (const float*)d_in[2];
    const float* Wk   = (const float*)d_in[3];
    const float* Wv   = (const float*)d_in[4];
    const float* Wout = (const float*)d_in[5];
    const float* lam  = (const float*)d_in[6];
    float* out = (float*)d_out;

    const size_t SD = (size_t)S_LEN * D_DIM;
    const size_t DD = (size_t)D_DIM * D_DIM;
    unsigned short* Qb  = (unsigned short*)d_ws;         // internal bf16, 4 MB
    unsigned short* Kb  = Qb + SD;                       // 4 MB
    unsigned short* Vtg = Kb + SD;                       // V transposed [D_DIM][S_LEN], 4 MB
    unsigned short* Ab  = Qb;                            // alias (block-private RW in attn)

    // bf16 scratch in d_out (16 MB f32): y slot holds Wq/Wk/Wv copies (6 MB,
    // overwritten by out-proj), v1 slot holds xb+Woutb (6 MB, overwritten by copy_v1).
    unsigned short* Wqb   = (unsigned short*)d_out;            // 2 MB
    unsigned short* Wkb   = Wqb + DD;                          // 2 MB
    unsigned short* Wvb   = Wkb + DD;                          // 2 MB
    unsigned short* xb    = (unsigned short*)(out + SD);       // 4 MB
    unsigned short* Woutb = xb + SD;                           // 2 MB

    to_bf16<<<dim3(1024, 5), 256, 0, stream>>>(
        x, Wq, Wk, Wv, Wout, xb, Wqb, Wkb, Wvb, Woutb);

    // Q/K/V projections; Q,K get fused RMSNorm+RoPE; V gets fused v-mix + transpose.
    gemm_bt<<<dim3(D_DIM / 128, S_LEN / 128, 3), 256, 0, stream>>>(
        xb, Wqb, Wkb, Wvb, Qb, Kb, Vtg, v1, lam,
        EPI_NORMROPE | (EPI_NORMROPE << 8) | (EPI_VMIX_T << 16));

    attn_mfma<<<dim3(2048), 64, 0, stream>>>(Qb, Kb, Vtg, Ab);

    // output projection -> y slot, f32
    gemm_bt<<<dim3(D_DIM / 128, S_LEN / 128, 1), 256, 0, stream>>>(
        Ab, Woutb, Woutb, Woutb, d_out, d_out, d_out, nullptr, lam, EPI_F32);

    copy_v1<<<dim3((unsigned)(SD / 4 / 256)), 256, 0, stream>>>(
        (const uint4*)v1, (uint4*)(out + SD));
}

// Round 10
// 181.896 us; speedup vs baseline: 1.5177x; 1.5177x over previous
//
#include <hip/hip_runtime.h>
#include <hip/hip_bf16.h>

#define S_LEN 2048
#define D_DIM 1024
#define NH    16
#define NEG_BIG (-1.0e30f)

// epilogue modes for gemm_bt
#define EPI_NORMROPE 1   // RMSNorm + RoPE, store bf16 row-major (Q,K)
#define EPI_VMIX_T   2   // v-mix with v1, store bf16 TRANSPOSED (V -> Vt_g[d][s])
#define EPI_F32      3   // plain f32 row-major store (out-proj)

typedef __attribute__((ext_vector_type(8))) short bf16x8;
typedef __attribute__((ext_vector_type(4))) float f32x4;
typedef const __attribute__((address_space(1))) unsigned char gu8_t;
typedef __attribute__((address_space(3))) unsigned char lu8_t;

__device__ __forceinline__ float bf2f(unsigned short h) {
    union { unsigned int u; float f; } v; v.u = ((unsigned int)h) << 16; return v.f;
}
__device__ __forceinline__ unsigned short f2b(float f) {   // RNE f32->bf16 raw bits
    union { float f; unsigned int u; } v; v.f = f;
    unsigned int u = v.u;
    return (unsigned short)((u + 0x7FFFu + ((u >> 16) & 1u)) >> 16);
}

// one-shot f32 -> bf16 conversion of x + 4 weights (externals measured f32, r4-r9).
__global__ __launch_bounds__(256)
void to_bf16(const float* __restrict__ x,  const float* __restrict__ wq,
             const float* __restrict__ wk, const float* __restrict__ wv,
             const float* __restrict__ wo,
             unsigned short* __restrict__ xb,  unsigned short* __restrict__ wqb,
             unsigned short* __restrict__ wkb, unsigned short* __restrict__ wvb,
             unsigned short* __restrict__ wob)
{
    const int z = blockIdx.y;
    const float* s; unsigned short* d; int n;
    switch (z) {
        case 0: s = x;  d = xb;  n = S_LEN * D_DIM; break;
        case 1: s = wq; d = wqb; n = D_DIM * D_DIM; break;
        case 2: s = wk; d = wkb; n = D_DIM * D_DIM; break;
        case 3: s = wv; d = wvb; n = D_DIM * D_DIM; break;
        default: s = wo; d = wob; n = D_DIM * D_DIM; break;
    }
    int i8 = blockIdx.x * 256 + threadIdx.x;
    if (i8 * 8 >= n) return;
    const float* sp = s + (size_t)i8 * 8;
    float4 lo = *(const float4*)sp, hi = *(const float4*)(sp + 4);
    uint4 p;
    p.x = f2b(lo.x) | ((unsigned)f2b(lo.y) << 16);
    p.y = f2b(lo.z) | ((unsigned)f2b(lo.w) << 16);
    p.z = f2b(hi.x) | ((unsigned)f2b(hi.y) << 16);
    p.w = f2b(hi.z) | ((unsigned)f2b(hi.w) << 16);
    *(uint4*)(d + (size_t)i8 * 8) = p;
}

// C = A[M,K] * B[N,K]^T, bf16 inputs, global_load_lds(16B) staging into
// unpadded [128][32] LDS (m97 contract). Epilogue per 'epi' (wave-uniform).
__global__ __launch_bounds__(256, 2)
void gemm_bt(const unsigned short* __restrict__ A,
             const unsigned short* __restrict__ B0, const unsigned short* __restrict__ B1,
             const unsigned short* __restrict__ B2,
             void* __restrict__ C0, void* __restrict__ C1, void* __restrict__ C2,
             const float* __restrict__ vmix, const float* __restrict__ lam,
             int epiPack)
{
    const int which = blockIdx.z;
    const unsigned short* Bp = (which == 0) ? B0 : ((which == 1) ? B1 : B2);
    void* C = (which == 0) ? C0 : ((which == 1) ? C1 : C2);
    const int epi = (epiPack >> (8 * which)) & 0xff;
    const int tn = blockIdx.x * 128;
    const int tm = blockIdx.y * 128;

    __shared__ unsigned short Asl[128 * 32];   // unpadded: global_load_lds contract
    __shared__ unsigned short Bsl[128 * 32];

    const int t    = threadIdx.x;
    const int lane = t & 63;
    const int wave = t >> 6;
    const int wm   = (wave >> 1) * 64;
    const int wn   = (wave & 1) * 64;
    const int lrow = lane & 15;
    const int quad = lane >> 4;
    const int srow = lane >> 2;
    const int scol = (lane & 3) * 8;

    f32x4 acc[4][4];
    #pragma unroll
    for (int i = 0; i < 4; ++i)
        #pragma unroll
        for (int j = 0; j < 4; ++j) {
            f32x4 z = {0.f, 0.f, 0.f, 0.f};
            acc[i][j] = z;
        }

    for (int k0 = 0; k0 < D_DIM; k0 += 32) {
        #pragma unroll
        for (int rep = 0; rep < 2; ++rep) {
            int grp = wave * 2 + rep;               // 0..7 (16 rows each)
            int row = grp * 16 + srow;
            __builtin_amdgcn_global_load_lds(
                (gu8_t*)(A + (size_t)(tm + row) * D_DIM + k0 + scol),
                (lu8_t*)&Asl[grp * 512], 16, 0, 0);
            __builtin_amdgcn_global_load_lds(
                (gu8_t*)(Bp + (size_t)(tn + row) * D_DIM + k0 + scol),
                (lu8_t*)&Bsl[grp * 512], 16, 0, 0);
        }
        __syncthreads();
        bf16x8 af[4], bfr[4];
        #pragma unroll
        for (int i = 0; i < 4; ++i)
            af[i] = *(const bf16x8*)(&Asl[(wm + i * 16 + lrow) * 32 + quad * 8]);
        #pragma unroll
        for (int j = 0; j < 4; ++j)
            bfr[j] = *(const bf16x8*)(&Bsl[(wn + j * 16 + lrow) * 32 + quad * 8]);
        #pragma unroll
        for (int i = 0; i < 4; ++i)
            #pragma unroll
            for (int j = 0; j < 4; ++j)
                acc[i][j] = __builtin_amdgcn_mfma_f32_16x16x32_bf16(af[i], bfr[j], acc[i][j], 0, 0, 0);
        __syncthreads();
    }

    if (epi == EPI_NORMROPE) {
        // wave covers cols [tn+wn, tn+wn+64) = one head. RoPE pair (i, i+32) = (j, j+2).
        #pragma unroll
        for (int i = 0; i < 4; ++i) {
            #pragma unroll
            for (int r = 0; r < 4; ++r) {
                int row = tm + wm + i * 16 + quad * 4 + r;   // seq position (m89/m91 C-map)
                float v0 = acc[i][0][r], v1 = acc[i][1][r];
                float v2 = acc[i][2][r], v3 = acc[i][3][r];
                float ss = v0 * v0 + v1 * v1 + v2 * v2 + v3 * v3;
                ss += __shfl_xor(ss, 1); ss += __shfl_xor(ss, 2);
                ss += __shfl_xor(ss, 4); ss += __shfl_xor(ss, 8);   // 16-lane group = full head
                float rms = rsqrtf(ss * (1.f / 64.f) + 1.1920929e-7f);
                v0 *= rms; v1 *= rms; v2 *= rms; v3 *= rms;
                float fs = (float)row;
                float a0 = fs * exp2f(-0.41524101186092030f * (float)lrow);        // 10000^(-2i/64)
                float a1 = fs * exp2f(-0.41524101186092030f * (float)(16 + lrow));
                float s0, c0, s1, c1;
                __sincosf(a0, &s0, &c0);
                __sincosf(a1, &s1, &c1);
                unsigned short* Cb = (unsigned short*)C;
                size_t base = (size_t)row * D_DIM + tn + wn + lrow;
                Cb[base]      = f2b(v0 * c0 + v2 * s0);
                Cb[base + 16] = f2b(v1 * c1 + v3 * s1);
                Cb[base + 32] = f2b(-v0 * s0 + v2 * c0);
                Cb[base + 48] = f2b(-v1 * s1 + v3 * c1);
            }
        }
    } else if (epi == EPI_VMIX_T) {
        float lamf = *lam;
        #pragma unroll
        for (int i = 0; i < 4; ++i) {
            int cm0 = tm + wm + i * 16 + quad * 4;
            #pragma unroll
            for (int j = 0; j < 4; ++j) {
                int cn = tn + wn + j * 16 + lrow;
                ushort4 pk;
                float vals[4];
                #pragma unroll
                for (int r = 0; r < 4; ++r) {
                    size_t idx = (size_t)(cm0 + r) * D_DIM + cn;
                    vals[r] = (1.f - lamf) * acc[i][j][r] + lamf * vmix[idx];
                }
                pk.x = f2b(vals[0]); pk.y = f2b(vals[1]);
                pk.z = f2b(vals[2]); pk.w = f2b(vals[3]);
                *(ushort4*)((unsigned short*)C + (size_t)cn * S_LEN + cm0) = pk;
            }
        }
    } else {   // EPI_F32
        #pragma unroll
        for (int i = 0; i < 4; ++i) {
            int cm0 = tm + wm + i * 16 + quad * 4;
            #pragma unroll
            for (int j = 0; j < 4; ++j) {
                int cn = tn + wn + j * 16 + lrow;
                #pragma unroll
                for (int r = 0; r < 4; ++r)
                    ((float*)C)[(size_t)(cm0 + r) * D_DIM + cn] = acc[i][j][r];
            }
        }
    }
}

// MFMA flash attention, 64-key LDS tiles, 4 waves/block (r8 structure — best
// measured), with STATIC-MAX softmax: RMSNorm + RoPE => |score| <= 8 always,
// so p = exp(s - 8) needs no running max, no alpha rescale, and the l-sum is a
// per-lane accumulator reduced ONCE after the loop. Removes both per-tile
// shfl-reduction latency chains from the critical path.
__global__ __launch_bounds__(256, 2)
void attn_mfma(const unsigned short* Qb,
               const unsigned short* __restrict__ Kb,
               const unsigned short* __restrict__ Vtg,
               unsigned short* Ob)
{
    const int bx = blockIdx.x;
    const int qt = (bx & 1) ? (31 - (bx >> 1)) : (bx >> 1);  // pair big+small tiles
    const int h  = blockIdx.y;
    const int t  = threadIdx.x;
    const int w  = t >> 6;
    const int l  = t & 63;
    const int l15  = l & 15;
    const int quad = l >> 4;
    const int hco  = h * 64;

    __shared__ unsigned short Ks[64][72];
    __shared__ unsigned short Vt[64][72];       // Vt[d][key]
    __shared__ unsigned short Ps[4][16][72];    // per-wave P tile

    const unsigned short* qrow = Qb + (size_t)(qt * 64 + w * 16 + l15) * D_DIM + hco;
    bf16x8 qf0 = *(const bf16x8*)(qrow + quad * 8);
    bf16x8 qf1 = *(const bf16x8*)(qrow + 32 + quad * 8);

    f32x4 oac[4];
    #pragma unroll
    for (int nt = 0; nt < 4; ++nt) { f32x4 z = {0.f,0.f,0.f,0.f}; oac[nt] = z; }
    float l_lane[4] = {0.f, 0.f, 0.f, 0.f};     // per-lane partial softmax sums

    const int rr = t >> 2;          // staging row (K: key row; Vt: d row)
    const int dc = (t & 3) * 16;    // 16-col group

    const unsigned short* kbase = Kb  + (size_t)rr * D_DIM + hco + dc;
    const unsigned short* vbase = Vtg + (size_t)(hco + rr) * S_LEN + dc;

    uint4 ka0, ka1, va0, va1;
    ka0 = *(const uint4*)kbase;  ka1 = *(const uint4*)(kbase + 8);
    va0 = *(const uint4*)vbase;  va1 = *(const uint4*)(vbase + 8);

    const int row_base = qt * 64 + w * 16 + quad * 4;   // C-layout row = quad*4 + reg

    for (int j = 0; j <= qt; ++j) {
        __syncthreads();
        *(uint4*)&Ks[rr][dc]     = ka0;
        *(uint4*)&Ks[rr][dc + 8] = ka1;
        *(uint4*)&Vt[rr][dc]     = va0;
        *(uint4*)&Vt[rr][dc + 8] = va1;
        __syncthreads();
        if (j < qt) {
            const unsigned short* kp = kbase + (size_t)(j + 1) * 64 * D_DIM;
            const unsigned short* vp = vbase + (size_t)(j + 1) * 64;
            ka0 = *(const uint4*)kp;  ka1 = *(const uint4*)(kp + 8);
            va0 = *(const uint4*)vp;  va1 = *(const uint4*)(vp + 8);
        }

        // S = Q K^T (16 rows x 64 keys)
        f32x4 sac[4];
        #pragma unroll
        for (int nt = 0; nt < 4; ++nt) {
            f32x4 z = {0.f,0.f,0.f,0.f};
            bf16x8 kf0 = *(const bf16x8*)&Ks[nt * 16 + l15][quad * 8];
            z = __builtin_amdgcn_mfma_f32_16x16x32_bf16(qf0, kf0, z, 0, 0, 0);
            bf16x8 kf1 = *(const bf16x8*)&Ks[nt * 16 + l15][32 + quad * 8];
            z = __builtin_amdgcn_mfma_f32_16x16x32_bf16(qf1, kf1, z, 0, 0, 0);
            sac[nt] = z;
        }

        // static-max softmax: p = exp(s/8 - 8); mask -> exp(NEG_BIG) = 0.
        #pragma unroll
        for (int nt = 0; nt < 4; ++nt) {
            int key_g = j * 64 + nt * 16 + l15;
            #pragma unroll
            for (int r = 0; r < 4; ++r) {
                float s = sac[nt][r] * 0.125f - 8.0f;
                if (key_g > row_base + r) s = NEG_BIG;
                float pe = __expf(s);
                l_lane[r] += pe;
                Ps[w][quad * 4 + r][nt * 16 + l15] = f2b(pe);
            }
        }

        // P: C-layout -> A-layout via per-wave LDS, then PV (no rescale needed)
        bf16x8 pf0 = *(const bf16x8*)&Ps[w][l15][quad * 8];
        bf16x8 pf1 = *(const bf16x8*)&Ps[w][l15][32 + quad * 8];
        #pragma unroll
        for (int nt = 0; nt < 4; ++nt) {
            bf16x8 vf0 = *(const bf16x8*)&Vt[nt * 16 + l15][quad * 8];
            oac[nt] = __builtin_amdgcn_mfma_f32_16x16x32_bf16(pf0, vf0, oac[nt], 0, 0, 0);
            bf16x8 vf1 = *(const bf16x8*)&Vt[nt * 16 + l15][32 + quad * 8];
            oac[nt] = __builtin_amdgcn_mfma_f32_16x16x32_bf16(pf1, vf1, oac[nt], 0, 0, 0);
        }
    }

    // one l-reduction for the whole kernel (row sum lives across the 16-lane group)
    float inv[4];
    #pragma unroll
    for (int r = 0; r < 4; ++r) {
        float lr = l_lane[r];
        #pragma unroll
        for (int d = 1; d < 16; d <<= 1) lr += __shfl_xor(lr, d);
        inv[r] = 1.f / lr;   // > 0: diagonal key contributes exp(s-8) >= exp(-16)
    }
    #pragma unroll
    for (int nt = 0; nt < 4; ++nt) {
        #pragma unroll
        for (int r = 0; r < 4; ++r) {
            int row_g = row_base + r;
            Ob[(size_t)row_g * D_DIM + hco + nt * 16 + l15] = f2b(oac[nt][r] * inv[r]);
        }
    }
}

// v1 passthrough (f32), 16B chunks.
__global__ __launch_bounds__(256)
void copy_v1(const uint4* __restrict__ src, uint4* __restrict__ dst) {
    int i = blockIdx.x * 256 + threadIdx.x;
    dst[i] = src[i];
}

extern "C" void kernel_launch(void* const* d_in, const int* in_sizes, int n_in,
                              void* d_out, int out_size, void* d_ws, size_t ws_size,
                              hipStream_t stream)
{
    const float* x    = (const float*)d_in[0];
    const float* v1   = (const float*)d_in[1];
    const float* Wq   = (const float*)d_in[2];
    const float* Wk   = (const float*)d_in[3];
    const float* Wv   = (const float*)d_in[4];
    const float* Wout = (const float*)d_in[5];
    const float* lam  = (const float*)d_in[6];
    float* out = (float*)d_out;

    const size_t SD = (size_t)S_LEN * D_DIM;
    const size_t DD = (size_t)D_DIM * D_DIM;
    unsigned short* Qb  = (unsigned short*)d_ws;         // internal bf16, 4 MB
    unsigned short* Kb  = Qb + SD;                       // 4 MB
    unsigned short* Vtg = Kb + SD;                       // V transposed [D_DIM][S_LEN], 4 MB
    unsigned short* Ab  = Qb;                            // alias (block-private RW in attn)

    // bf16 scratch in d_out (16 MB f32): y slot holds Wq/Wk/Wv copies (6 MB,
    // overwritten by out-proj), v1 slot holds xb+Woutb (6 MB, overwritten by copy_v1).
    unsigned short* Wqb   = (unsigned short*)d_out;            // 2 MB
    unsigned short* Wkb   = Wqb + DD;                          // 2 MB
    unsigned short* Wvb   = Wkb + DD;                          // 2 MB
    unsigned short* xb    = (unsigned short*)(out + SD);       // 4 MB
    unsigned short* Woutb = xb + SD;                           // 2 MB

    to_bf16<<<dim3(1024, 5), 256, 0, stream>>>(
        x, Wq, Wk, Wv, Wout, xb, Wqb, Wkb, Wvb, Woutb);

    // Q/K/V projections; Q,K get fused RMSNorm+RoPE; V gets fused v-mix + transpose.
    gemm_bt<<<dim3(D_DIM / 128, S_LEN / 128, 3), 256, 0, stream>>>(
        xb, Wqb, Wkb, Wvb, Qb, Kb, Vtg, v1, lam,
        EPI_NORMROPE | (EPI_NORMROPE << 8) | (EPI_VMIX_T << 16));

    attn_mfma<<<dim3(S_LEN / 64, NH), 256, 0, stream>>>(Qb, Kb, Vtg, Ab);

    // output projection -> y slot, f32
    gemm_bt<<<dim3(D_DIM / 128, S_LEN / 128, 1), 256, 0, stream>>>(
        Ab, Woutb, Woutb, Woutb, d_out, d_out, d_out, nullptr, lam, EPI_F32);

    copy_v1<<<dim3((unsigned)(SD / 4 / 256)), 256, 0, stream>>>(
        (const uint4*)v1, (uint4*)(out + SD));
}

// Round 11
// 180.368 us; speedup vs baseline: 1.5305x; 1.0085x over previous
//
#include <hip/hip_runtime.h>
#include <hip/hip_bf16.h>

#define S_LEN 2048
#define D_DIM 1024
#define NH    16
#define NEG_BIG (-1.0e30f)

// epilogue modes for gemm_bt
#define EPI_NORMROPE   1   // RMSNorm + RoPE, store bf16 row-major (K)
#define EPI_VMIX_T     2   // v-mix with v1, store bf16 TRANSPOSED (V -> Vt_g[d][s])
#define EPI_F32        3   // plain f32 row-major store (out-proj)
#define EPI_NORMROPE_Q 4   // like NORMROPE but pre-scaled by 0.125*log2e (Q)

typedef __attribute__((ext_vector_type(8))) short bf16x8;
typedef __attribute__((ext_vector_type(4))) float f32x4;
typedef const __attribute__((address_space(1))) unsigned char gu8_t;
typedef __attribute__((address_space(3))) unsigned char lu8_t;

__device__ __forceinline__ float bf2f(unsigned short h) {
    union { unsigned int u; float f; } v; v.u = ((unsigned int)h) << 16; return v.f;
}
__device__ __forceinline__ unsigned short f2b(float f) {   // RNE f32->bf16 raw bits
    union { float f; unsigned int u; } v; v.f = f;
    unsigned int u = v.u;
    return (unsigned short)((u + 0x7FFFu + ((u >> 16) & 1u)) >> 16);
}
__device__ __forceinline__ unsigned short f2b_trunc(float f) {  // trunc (p>=0 only)
    union { float f; unsigned int u; } v; v.f = f;
    return (unsigned short)(v.u >> 16);
}

// one-shot f32 -> bf16 conversion of x + 4 weights (externals measured f32, r4-r10).
__global__ __launch_bounds__(256)
void to_bf16(const float* __restrict__ x,  const float* __restrict__ wq,
             const float* __restrict__ wk, const float* __restrict__ wv,
             const float* __restrict__ wo,
             unsigned short* __restrict__ xb,  unsigned short* __restrict__ wqb,
             unsigned short* __restrict__ wkb, unsigned short* __restrict__ wvb,
             unsigned short* __restrict__ wob)
{
    const int z = blockIdx.y;
    const float* s; unsigned short* d; int n;
    switch (z) {
        case 0: s = x;  d = xb;  n = S_LEN * D_DIM; break;
        case 1: s = wq; d = wqb; n = D_DIM * D_DIM; break;
        case 2: s = wk; d = wkb; n = D_DIM * D_DIM; break;
        case 3: s = wv; d = wvb; n = D_DIM * D_DIM; break;
        default: s = wo; d = wob; n = D_DIM * D_DIM; break;
    }
    int i8 = blockIdx.x * 256 + threadIdx.x;
    if (i8 * 8 >= n) return;
    const float* sp = s + (size_t)i8 * 8;
    float4 lo = *(const float4*)sp, hi = *(const float4*)(sp + 4);
    uint4 p;
    p.x = f2b(lo.x) | ((unsigned)f2b(lo.y) << 16);
    p.y = f2b(lo.z) | ((unsigned)f2b(lo.w) << 16);
    p.z = f2b(hi.x) | ((unsigned)f2b(hi.y) << 16);
    p.w = f2b(hi.z) | ((unsigned)f2b(hi.w) << 16);
    *(uint4*)(d + (size_t)i8 * 8) = p;
}

// C = A[M,K] * B[N,K]^T, bf16 inputs, global_load_lds(16B) staging into
// unpadded [128][32] LDS (m97 contract). Epilogue per 'epi' (wave-uniform).
__global__ __launch_bounds__(256, 3)
void gemm_bt(const unsigned short* __restrict__ A,
             const unsigned short* __restrict__ B0, const unsigned short* __restrict__ B1,
             const unsigned short* __restrict__ B2,
             void* __restrict__ C0, void* __restrict__ C1, void* __restrict__ C2,
             const float* __restrict__ vmix, const float* __restrict__ lam,
             int epiPack)
{
    const int which = blockIdx.z;
    const unsigned short* Bp = (which == 0) ? B0 : ((which == 1) ? B1 : B2);
    void* C = (which == 0) ? C0 : ((which == 1) ? C1 : C2);
    const int epi = (epiPack >> (8 * which)) & 0xff;
    const int tn = blockIdx.x * 128;
    const int tm = blockIdx.y * 128;

    __shared__ unsigned short Asl[128 * 32];   // unpadded: global_load_lds contract
    __shared__ unsigned short Bsl[128 * 32];

    const int t    = threadIdx.x;
    const int lane = t & 63;
    const int wave = t >> 6;
    const int wm   = (wave >> 1) * 64;
    const int wn   = (wave & 1) * 64;
    const int lrow = lane & 15;
    const int quad = lane >> 4;
    const int srow = lane >> 2;
    const int scol = (lane & 3) * 8;

    f32x4 acc[4][4];
    #pragma unroll
    for (int i = 0; i < 4; ++i)
        #pragma unroll
        for (int j = 0; j < 4; ++j) {
            f32x4 z = {0.f, 0.f, 0.f, 0.f};
            acc[i][j] = z;
        }

    for (int k0 = 0; k0 < D_DIM; k0 += 32) {
        #pragma unroll
        for (int rep = 0; rep < 2; ++rep) {
            int grp = wave * 2 + rep;               // 0..7 (16 rows each)
            int row = grp * 16 + srow;
            __builtin_amdgcn_global_load_lds(
                (gu8_t*)(A + (size_t)(tm + row) * D_DIM + k0 + scol),
                (lu8_t*)&Asl[grp * 512], 16, 0, 0);
            __builtin_amdgcn_global_load_lds(
                (gu8_t*)(Bp + (size_t)(tn + row) * D_DIM + k0 + scol),
                (lu8_t*)&Bsl[grp * 512], 16, 0, 0);
        }
        __syncthreads();
        bf16x8 af[4], bfr[4];
        #pragma unroll
        for (int i = 0; i < 4; ++i)
            af[i] = *(const bf16x8*)(&Asl[(wm + i * 16 + lrow) * 32 + quad * 8]);
        #pragma unroll
        for (int j = 0; j < 4; ++j)
            bfr[j] = *(const bf16x8*)(&Bsl[(wn + j * 16 + lrow) * 32 + quad * 8]);
        #pragma unroll
        for (int i = 0; i < 4; ++i)
            #pragma unroll
            for (int j = 0; j < 4; ++j)
                acc[i][j] = __builtin_amdgcn_mfma_f32_16x16x32_bf16(af[i], bfr[j], acc[i][j], 0, 0, 0);
        __syncthreads();
    }

    if (epi == EPI_NORMROPE || epi == EPI_NORMROPE_Q) {
        // wave covers cols [tn+wn, tn+wn+64) = one head. RoPE pair (i, i+32) = (j, j+2).
        // Q variant folds 0.125*log2e into rms: rope is linear, scale commutes;
        // attention scores then land directly in the log2 domain (see attn_mfma).
        const float post = (epi == EPI_NORMROPE_Q) ? 0.18033688011112042f : 1.0f;
        #pragma unroll
        for (int i = 0; i < 4; ++i) {
            #pragma unroll
            for (int r = 0; r < 4; ++r) {
                int row = tm + wm + i * 16 + quad * 4 + r;   // seq position (m89/m91 C-map)
                float v0 = acc[i][0][r], v1 = acc[i][1][r];
                float v2 = acc[i][2][r], v3 = acc[i][3][r];
                float ss = v0 * v0 + v1 * v1 + v2 * v2 + v3 * v3;
                ss += __shfl_xor(ss, 1); ss += __shfl_xor(ss, 2);
                ss += __shfl_xor(ss, 4); ss += __shfl_xor(ss, 8);   // 16-lane group = full head
                float rms = rsqrtf(ss * (1.f / 64.f) + 1.1920929e-7f) * post;
                v0 *= rms; v1 *= rms; v2 *= rms; v3 *= rms;
                float fs = (float)row;
                float a0 = fs * exp2f(-0.41524101186092030f * (float)lrow);        // 10000^(-2i/64)
                float a1 = fs * exp2f(-0.41524101186092030f * (float)(16 + lrow));
                float s0, c0, s1, c1;
                __sincosf(a0, &s0, &c0);
                __sincosf(a1, &s1, &c1);
                unsigned short* Cb = (unsigned short*)C;
                size_t base = (size_t)row * D_DIM + tn + wn + lrow;
                Cb[base]      = f2b(v0 * c0 + v2 * s0);
                Cb[base + 16] = f2b(v1 * c1 + v3 * s1);
                Cb[base + 32] = f2b(-v0 * s0 + v2 * c0);
                Cb[base + 48] = f2b(-v1 * s1 + v3 * c1);
            }
        }
    } else if (epi == EPI_VMIX_T) {
        float lamf = *lam;
        #pragma unroll
        for (int i = 0; i < 4; ++i) {
            int cm0 = tm + wm + i * 16 + quad * 4;
            #pragma unroll
            for (int j = 0; j < 4; ++j) {
                int cn = tn + wn + j * 16 + lrow;
                ushort4 pk;
                float vals[4];
                #pragma unroll
                for (int r = 0; r < 4; ++r) {
                    size_t idx = (size_t)(cm0 + r) * D_DIM + cn;
                    vals[r] = (1.f - lamf) * acc[i][j][r] + lamf * vmix[idx];
                }
                pk.x = f2b(vals[0]); pk.y = f2b(vals[1]);
                pk.z = f2b(vals[2]); pk.w = f2b(vals[3]);
                *(ushort4*)((unsigned short*)C + (size_t)cn * S_LEN + cm0) = pk;
            }
        }
    } else {   // EPI_F32
        #pragma unroll
        for (int i = 0; i < 4; ++i) {
            int cm0 = tm + wm + i * 16 + quad * 4;
            #pragma unroll
            for (int j = 0; j < 4; ++j) {
                int cn = tn + wn + j * 16 + lrow;
                #pragma unroll
                for (int r = 0; r < 4; ++r)
                    ((float*)C)[(size_t)(cm0 + r) * D_DIM + cn] = acc[i][j][r];
            }
        }
    }
}

// MFMA flash attention: 64-key DOUBLE-BUFFERED LDS tiles, ONE barrier/iter.
// Static-max softmax in log2 domain (Q pre-scaled by 0.125*log2e in its GEMM
// epilogue): p = exp2(sac - 8*log2e). Mask applied only in the diagonal j-tile.
// l-sum: per-lane accumulator, reduced once after the loop.
__global__ __launch_bounds__(256, 2)
void attn_mfma(const unsigned short* Qb,
               const unsigned short* __restrict__ Kb,
               const unsigned short* __restrict__ Vtg,
               unsigned short* Ob)
{
    const int bx = blockIdx.x;
    const int qt = (bx & 1) ? (31 - (bx >> 1)) : (bx >> 1);  // pair big+small tiles
    const int h  = blockIdx.y;
    const int t  = threadIdx.x;
    const int w  = t >> 6;
    const int l  = t & 63;
    const int l15  = l & 15;
    const int quad = l >> 4;
    const int hco  = h * 64;

    __shared__ unsigned short Ks[2][64][72];    // double-buffered
    __shared__ unsigned short Vt[2][64][72];    // Vt[buf][d][key]
    __shared__ unsigned short Ps[4][16][72];    // per-wave P tile (wave-private)

    const unsigned short* qrow = Qb + (size_t)(qt * 64 + w * 16 + l15) * D_DIM + hco;
    bf16x8 qf0 = *(const bf16x8*)(qrow + quad * 8);
    bf16x8 qf1 = *(const bf16x8*)(qrow + 32 + quad * 8);

    f32x4 oac[4];
    #pragma unroll
    for (int nt = 0; nt < 4; ++nt) { f32x4 z = {0.f,0.f,0.f,0.f}; oac[nt] = z; }
    float l_lane[4] = {0.f, 0.f, 0.f, 0.f};

    const int rr = t >> 2;          // staging row (K: key row; Vt: d row)
    const int dc = (t & 3) * 16;    // 16-col group

    const unsigned short* kbase = Kb  + (size_t)rr * D_DIM + hco + dc;
    const unsigned short* vbase = Vtg + (size_t)(hco + rr) * S_LEN + dc;

    uint4 ka0, ka1, va0, va1;
    ka0 = *(const uint4*)kbase;  ka1 = *(const uint4*)(kbase + 8);
    va0 = *(const uint4*)vbase;  va1 = *(const uint4*)(vbase + 8);

    const int row_base = qt * 64 + w * 16 + quad * 4;   // C-layout row = quad*4 + reg
    const float C2 = -11.541560327111707f;              // -8 * log2(e)

    // j loop: bulk (unmasked) iterations j=0..qt-1, then masked diagonal j=qt.
    for (int j = 0; j <= qt; ++j) {
        const int buf = j & 1;
        // write this tile's LDS from prefetched regs (vmcnt wait auto-inserted)
        *(uint4*)&Ks[buf][rr][dc]     = ka0;
        *(uint4*)&Ks[buf][rr][dc + 8] = ka1;
        *(uint4*)&Vt[buf][rr][dc]     = va0;
        *(uint4*)&Vt[buf][rr][dc + 8] = va1;
        __syncthreads();                       // ONE barrier per iteration
        if (j < qt) {                          // prefetch next tile into regs
            const unsigned short* kp = kbase + (size_t)(j + 1) * 64 * D_DIM;
            const unsigned short* vp = vbase + (size_t)(j + 1) * 64;
            ka0 = *(const uint4*)kp;  ka1 = *(const uint4*)(kp + 8);
            va0 = *(const uint4*)vp;  va1 = *(const uint4*)(vp + 8);
        }

        // S = Q K^T (16 rows x 64 keys) — already in log2 domain (Q pre-scaled)
        f32x4 sac[4];
        #pragma unroll
        for (int nt = 0; nt < 4; ++nt) {
            f32x4 z = {0.f,0.f,0.f,0.f};
            bf16x8 kf0 = *(const bf16x8*)&Ks[buf][nt * 16 + l15][quad * 8];
            z = __builtin_amdgcn_mfma_f32_16x16x32_bf16(qf0, kf0, z, 0, 0, 0);
            bf16x8 kf1 = *(const bf16x8*)&Ks[buf][nt * 16 + l15][32 + quad * 8];
            z = __builtin_amdgcn_mfma_f32_16x16x32_bf16(qf1, kf1, z, 0, 0, 0);
            sac[nt] = z;
        }

        if (j < qt) {
            // bulk: no masking needed
            #pragma unroll
            for (int nt = 0; nt < 4; ++nt) {
                #pragma unroll
                for (int r = 0; r < 4; ++r) {
                    float pe = exp2f(sac[nt][r] + C2);
                    l_lane[r] += pe;
                    Ps[w][quad * 4 + r][nt * 16 + l15] = f2b_trunc(pe);
                }
            }
        } else {
            // diagonal tile: causal mask
            #pragma unroll
            for (int nt = 0; nt < 4; ++nt) {
                int key_g = j * 64 + nt * 16 + l15;
                #pragma unroll
                for (int r = 0; r < 4; ++r) {
                    float s = sac[nt][r] + C2;
                    if (key_g > row_base + r) s = NEG_BIG;
                    float pe = exp2f(s);
                    l_lane[r] += pe;
                    Ps[w][quad * 4 + r][nt * 16 + l15] = f2b_trunc(pe);
                }
            }
        }

        // P: C-layout -> A-layout via per-wave LDS, then PV
        bf16x8 pf0 = *(const bf16x8*)&Ps[w][l15][quad * 8];
        bf16x8 pf1 = *(const bf16x8*)&Ps[w][l15][32 + quad * 8];
        #pragma unroll
        for (int nt = 0; nt < 4; ++nt) {
            bf16x8 vf0 = *(const bf16x8*)&Vt[buf][nt * 16 + l15][quad * 8];
            oac[nt] = __builtin_amdgcn_mfma_f32_16x16x32_bf16(pf0, vf0, oac[nt], 0, 0, 0);
            bf16x8 vf1 = *(const bf16x8*)&Vt[buf][nt * 16 + l15][32 + quad * 8];
            oac[nt] = __builtin_amdgcn_mfma_f32_16x16x32_bf16(pf1, vf1, oac[nt], 0, 0, 0);
        }
    }

    // one l-reduction for the whole kernel
    float inv[4];
    #pragma unroll
    for (int r = 0; r < 4; ++r) {
        float lr = l_lane[r];
        #pragma unroll
        for (int d = 1; d < 16; d <<= 1) lr += __shfl_xor(lr, d);
        inv[r] = 1.f / lr;   // > 0: diagonal key contributes exp2(s-11.54) > 0
    }
    #pragma unroll
    for (int nt = 0; nt < 4; ++nt) {
        #pragma unroll
        for (int r = 0; r < 4; ++r) {
            int row_g = row_base + r;
            Ob[(size_t)row_g * D_DIM + hco + nt * 16 + l15] = f2b(oac[nt][r] * inv[r]);
        }
    }
}

// v1 passthrough (f32), 16B chunks.
__global__ __launch_bounds__(256)
void copy_v1(const uint4* __restrict__ src, uint4* __restrict__ dst) {
    int i = blockIdx.x * 256 + threadIdx.x;
    dst[i] = src[i];
}

extern "C" void kernel_launch(void* const* d_in, const int* in_sizes, int n_in,
                              void* d_out, int out_size, void* d_ws, size_t ws_size,
                              hipStream_t stream)
{
    const float* x    = (const float*)d_in[0];
    const float* v1   = (const float*)d_in[1];
    const float* Wq   = (const float*)d_in[2];
    const float* Wk   = (const float*)d_in[3];
    const float* Wv   = (const float*)d_in[4];
    const float* Wout = (const float*)d_in[5];
    const float* lam  = (const float*)d_in[6];
    float* out = (float*)d_out;

    const size_t SD = (size_t)S_LEN * D_DIM;
    const size_t DD = (size_t)D_DIM * D_DIM;
    unsigned short* Qb  = (unsigned short*)d_ws;         // internal bf16, 4 MB
    unsigned short* Kb  = Qb + SD;                       // 4 MB
    unsigned short* Vtg = Kb + SD;                       // V transposed [D_DIM][S_LEN], 4 MB
    unsigned short* Ab  = Qb;                            // alias (block-private RW in attn)

    // bf16 scratch in d_out (16 MB f32): y slot holds Wq/Wk/Wv copies (6 MB,
    // overwritten by out-proj), v1 slot holds xb+Woutb (6 MB, overwritten by copy_v1).
    unsigned short* Wqb   = (unsigned short*)d_out;            // 2 MB
    unsigned short* Wkb   = Wqb + DD;                          // 2 MB
    unsigned short* Wvb   = Wkb + DD;                          // 2 MB
    unsigned short* xb    = (unsigned short*)(out + SD);       // 4 MB
    unsigned short* Woutb = xb + SD;                           // 2 MB

    to_bf16<<<dim3(1024, 5), 256, 0, stream>>>(
        x, Wq, Wk, Wv, Wout, xb, Wqb, Wkb, Wvb, Woutb);

    // Q/K/V projections; Q gets pre-scaled RMSNorm+RoPE, K plain, V v-mix + transpose.
    gemm_bt<<<dim3(D_DIM / 128, S_LEN / 128, 3), 256, 0, stream>>>(
        xb, Wqb, Wkb, Wvb, Qb, Kb, Vtg, v1, lam,
        EPI_NORMROPE_Q | (EPI_NORMROPE << 8) | (EPI_VMIX_T << 16));

    attn_mfma<<<dim3(S_LEN / 64, NH), 256, 0, stream>>>(Qb, Kb, Vtg, Ab);

    // output projection -> y slot, f32
    gemm_bt<<<dim3(D_DIM / 128, S_LEN / 128, 1), 256, 0, stream>>>(
        Ab, Woutb, Woutb, Woutb, d_out, d_out, d_out, nullptr, lam, EPI_F32);

    copy_v1<<<dim3((unsigned)(SD / 4 / 256)), 256, 0, stream>>>(
        (const uint4*)v1, (uint4*)(out + SD));
}